// Round 1
// 135.590 us; speedup vs baseline: 1.0158x; 1.0158x over previous
//
#include <hip/hip_runtime.h>
#include <math.h>

#define VOCAB 50000
#define D_WORD 300
#define D_TOPIC 128
#define DH 312            // D_NOUN_HIDDEN
#define NB 8192
#define LMAX 32
#define N_MONTH 12

// ---------------------------------------------------------------------------
// Kernel 1 (tiny): w = (k_w^T @ (q_w @ topic_emb + q_b)) * 1/sqrt(128).
// One block.  k_b and the month one-hot cancel in the softmax, so only
// w[0:300] feeds scores; the 1/sqrt(d_topic) score scale is folded in here.
// Vectorized q_w row reads (float4) + unrolled k_w column loop for MLP --
// this kernel is single-block, so it is pure latency; ILP is the lever.
// ---------------------------------------------------------------------------
__global__ __launch_bounds__(320) void compute_w_kernel(
    const float* __restrict__ topic_emb,
    const float* __restrict__ q_w, const float* __restrict__ q_b,
    const float* __restrict__ k_w,
    float* __restrict__ w_out)
{
    __shared__ float query_s[D_TOPIC];
    __shared__ float topic_s[D_TOPIC];
    int t = threadIdx.x;
    if (t < D_TOPIC) topic_s[t] = topic_emb[t];
    __syncthreads();
    if (t < D_TOPIC) {
        const float4* qr = (const float4*)(q_w + t * D_TOPIC);  // row-contig
        float q = q_b[t];
        #pragma unroll 8
        for (int k4 = 0; k4 < D_TOPIC / 4; ++k4) {
            float4 v = qr[k4];
            q = fmaf(v.x, topic_s[4 * k4 + 0], q);
            q = fmaf(v.y, topic_s[4 * k4 + 1], q);
            q = fmaf(v.z, topic_s[4 * k4 + 2], q);
            q = fmaf(v.w, topic_s[4 * k4 + 3], q);
        }
        query_s[t] = q;
    }
    __syncthreads();
    if (t < DH) {
        float acc = 0.f;
        #pragma unroll 8
        for (int d = 0; d < D_TOPIC; ++d)
            acc = fmaf(k_w[d * DH + t], query_s[d], acc);   // coalesced over t
        w_out[t] = acc * 0.08838834764831845f;              // 1/sqrt(128)
    }
}

// ---------------------------------------------------------------------------
// Kernel 2 (fused, single pass): one WAVE per sample, online softmax.
// Unrolled by TWO tokens per iteration:
//   - two independent we-row loads in flight (2x memory-level parallelism)
//   - two interleaved (independent) 6-step shuffle-reduce chains
//   - ONE combined flash rescale per pair:
//       mn = max3(m, p0, p1); acc = acc*c + e0*A + e1*B
//     halving the serial cross-iteration softmax-state chain.
// Odd tail handled by duplicating the last row and forcing p1 = -inf
// (e1 == 0), keeping the loop body uniform (no divergence; len is
// wave-uniform).  Month one-hot columns written directly (softmax sums
// to 1, so out[:,300+m] == encode * onehot(month)).
// ---------------------------------------------------------------------------
__global__ __launch_bounds__(256) void attn_fused_kernel(
    const int* __restrict__ noun_ids, const int* __restrict__ lengths,
    const int* __restrict__ months, const int* __restrict__ encode_p,
    const float* __restrict__ we, const float* __restrict__ w,
    float* __restrict__ out)
{
    int wave = threadIdx.x >> 6, lane = threadIdx.x & 63;
    int b = blockIdx.x * 4 + wave;
    float4* ob = (float4*)(out + (size_t)b * DH);   // 78 float4, 16B-aligned
    int len = lengths[b];

    if (len <= 0) {                       // reference leaves empty rows zero;
        float4 z = {0.f, 0.f, 0.f, 0.f};  // d_out is poisoned -> must write
        ob[lane] = z;
        if (lane < 14) ob[64 + lane] = z;
        return;                           // len uniform per wave: no divergence
    }
    if (len > LMAX) len = LMAX;

    // w fragment in registers (same cols as this lane's row fragment)
    const float4* w4 = (const float4*)w;
    float4 ww = w4[lane];
    float4 wb = (lane < 11) ? w4[64 + lane] : (float4){0.f, 0.f, 0.f, 0.f};

    int id = (lane < LMAX) ? noun_ids[b * LMAX + lane] : 0;

    float m = -1e30f, denom = 0.f;        // online-softmax state
    float4 acc0 = {0.f, 0.f, 0.f, 0.f};
    float4 acc1 = {0.f, 0.f, 0.f, 0.f};

    for (int l = 0; l < len; l += 2) {
        bool dual = (l + 1 < len);
        int rid0 = __shfl(id, l);
        int rid1 = __shfl(id, dual ? (l + 1) : l);  // dup last row on odd tail
        const float4* r0 = (const float4*)(we + (size_t)rid0 * D_WORD);
        const float4* r1 = (const float4*)(we + (size_t)rid1 * D_WORD);
        // issue all four loads up front -> two rows in flight
        float4 A0 = r0[lane];
        float4 B0 = r1[lane];
        float4 A1 = (lane < 11) ? r0[64 + lane] : (float4){0.f, 0.f, 0.f, 0.f};
        float4 B1 = (lane < 11) ? r1[64 + lane] : (float4){0.f, 0.f, 0.f, 0.f};

        // two independent inline scores (w pre-scaled by 1/sqrt(128))
        float p0 = fmaf(A0.x, ww.x, fmaf(A0.y, ww.y,
                   fmaf(A0.z, ww.z, fmaf(A0.w, ww.w,
                   fmaf(A1.x, wb.x, fmaf(A1.y, wb.y,
                   fmaf(A1.z, wb.z, A1.w * wb.w)))))));
        float p1 = fmaf(B0.x, ww.x, fmaf(B0.y, ww.y,
                   fmaf(B0.z, ww.z, fmaf(B0.w, ww.w,
                   fmaf(B1.x, wb.x, fmaf(B1.y, wb.y,
                   fmaf(B1.z, wb.z, B1.w * wb.w)))))));
        // interleaved independent reduce chains
        #pragma unroll
        for (int off = 32; off > 0; off >>= 1) {
            p0 += __shfl_xor(p0, off);
            p1 += __shfl_xor(p1, off);
        }
        if (!dual) p1 = -1e30f;           // tail: e1 -> 0, B contributes 0

        // ONE combined flash rescale for the pair
        float mn = fmaxf(fmaxf(m, p0), p1);   // v_max3_f32
        float c  = __expf(m  - mn);           // 0 on first iter (m = -1e30)
        float e0 = __expf(p0 - mn);
        float e1 = __expf(p1 - mn);
        m = mn;
        denom = fmaf(denom, c, e0 + e1);
        acc0.x = fmaf(acc0.x, c, fmaf(e0, A0.x, e1 * B0.x));
        acc0.y = fmaf(acc0.y, c, fmaf(e0, A0.y, e1 * B0.y));
        acc0.z = fmaf(acc0.z, c, fmaf(e0, A0.z, e1 * B0.z));
        acc0.w = fmaf(acc0.w, c, fmaf(e0, A0.w, e1 * B0.w));
        acc1.x = fmaf(acc1.x, c, fmaf(e0, A1.x, e1 * B1.x));
        acc1.y = fmaf(acc1.y, c, fmaf(e0, A1.y, e1 * B1.y));
        acc1.z = fmaf(acc1.z, c, fmaf(e0, A1.z, e1 * B1.z));
        acc1.w = fmaf(acc1.w, c, fmaf(e0, A1.w, e1 * B1.w));
    }

    float rs = 1.f / denom;
    acc0.x *= rs; acc0.y *= rs; acc0.z *= rs; acc0.w *= rs;
    ob[lane] = acc0;
    if (lane < 11) {
        acc1.x *= rs; acc1.y *= rs; acc1.z *= rs; acc1.w *= rs;
        ob[64 + lane] = acc1;
    } else if (lane < 14) {
        int mo = months[b];
        float enc = (float)(*encode_p);
        int base = (lane - 11) * 4;
        float4 oh;
        oh.x = (base + 0 == mo) ? enc : 0.f;
        oh.y = (base + 1 == mo) ? enc : 0.f;
        oh.z = (base + 2 == mo) ? enc : 0.f;
        oh.w = (base + 3 == mo) ? enc : 0.f;
        ob[64 + lane] = oh;
    }
}

// ---------------------------------------------------------------------------
extern "C" void kernel_launch(void* const* d_in, const int* in_sizes, int n_in,
                              void* d_out, int out_size, void* d_ws, size_t ws_size,
                              hipStream_t stream) {
    const float* topic_emb = (const float*)d_in[0];
    const int*   noun_ids  = (const int*)d_in[1];
    const int*   lengths   = (const int*)d_in[2];
    const int*   months    = (const int*)d_in[3];
    const int*   encode    = (const int*)d_in[4];
    const float* we        = (const float*)d_in[5];
    const float* k_w       = (const float*)d_in[6];
    // d_in[7] = k_b: cancels in softmax, never touches `value` -> unused.
    const float* q_w       = (const float*)d_in[8];
    const float* q_b       = (const float*)d_in[9];
    float* out = (float*)d_out;

    float* w_vec = (float*)d_ws;         // 312 floats

    compute_w_kernel<<<1, 320, 0, stream>>>(topic_emb, q_w, q_b, k_w, w_vec);
    attn_fused_kernel<<<NB / 4, 256, 0, stream>>>(noun_ids, lengths, months,
                                                  encode, we, w_vec, out);
}

// Round 2
// 134.869 us; speedup vs baseline: 1.0213x; 1.0053x over previous
//
#include <hip/hip_runtime.h>
#include <math.h>

#define VOCAB 50000
#define D_WORD 300
#define D_TOPIC 128
#define DH 312            // D_NOUN_HIDDEN
#define NB 8192
#define LMAX 32
#define N_MONTH 12

// ---------------------------------------------------------------------------
// Wave64 sum-reduce on the VALU pipe via DPP (no LDS-pipe ds_swizzle):
//   row_shr:1/2/4/8 accumulate within each 16-lane row, row_bcast:15/31
//   fold rows; full sum lands in lane 63; v_readlane broadcasts as SGPR.
// Chain: 6 VALU-rate ops (~25 cyc) vs 6 chained ds_swizzle (~hundreds).
// __builtin_amdgcn_update_dpp lets the compiler insert DPP hazard nops.
// ---------------------------------------------------------------------------
__device__ __forceinline__ float wave_sum_uniform(float x) {
    int v = __float_as_int(x);
    int t;
#define DPP_STEP(ctrl)                                                   \
    t = __builtin_amdgcn_update_dpp(0, v, (ctrl), 0xf, 0xf, true);       \
    v = __float_as_int(__int_as_float(v) + __int_as_float(t));
    DPP_STEP(0x111)   // row_shr:1
    DPP_STEP(0x112)   // row_shr:2
    DPP_STEP(0x114)   // row_shr:4
    DPP_STEP(0x118)   // row_shr:8
    DPP_STEP(0x142)   // row_bcast:15
    DPP_STEP(0x143)   // row_bcast:31
#undef DPP_STEP
    return __int_as_float(__builtin_amdgcn_readlane(v, 63));
}

// ---------------------------------------------------------------------------
// Kernel 1 (tiny): w = (k_w^T @ (q_w @ topic_emb + q_b)) * 1/sqrt(128).
// One block.  k_b and the month one-hot cancel in the softmax, so only
// w[0:300] feeds scores; the 1/sqrt(d_topic) score scale is folded in here.
// ---------------------------------------------------------------------------
__global__ __launch_bounds__(320) void compute_w_kernel(
    const float* __restrict__ topic_emb,
    const float* __restrict__ q_w, const float* __restrict__ q_b,
    const float* __restrict__ k_w,
    float* __restrict__ w_out)
{
    __shared__ float query_s[D_TOPIC];
    __shared__ float topic_s[D_TOPIC];
    int t = threadIdx.x;
    if (t < D_TOPIC) topic_s[t] = topic_emb[t];
    __syncthreads();
    if (t < D_TOPIC) {
        const float4* qr = (const float4*)(q_w + t * D_TOPIC);  // row-contig
        float q = q_b[t];
        #pragma unroll 8
        for (int k4 = 0; k4 < D_TOPIC / 4; ++k4) {
            float4 v = qr[k4];
            q = fmaf(v.x, topic_s[4 * k4 + 0], q);
            q = fmaf(v.y, topic_s[4 * k4 + 1], q);
            q = fmaf(v.z, topic_s[4 * k4 + 2], q);
            q = fmaf(v.w, topic_s[4 * k4 + 3], q);
        }
        query_s[t] = q;
    }
    __syncthreads();
    if (t < DH) {
        float acc = 0.f;
        #pragma unroll 8
        for (int d = 0; d < D_TOPIC; ++d)
            acc = fmaf(k_w[d * DH + t], query_s[d], acc);   // coalesced over t
        w_out[t] = acc * 0.08838834764831845f;              // 1/sqrt(128)
    }
}

// ---------------------------------------------------------------------------
// Kernel 2 (fused, single pass): one WAVE per sample, online softmax.
// Two tokens per iteration (2x MLP on the row loads), DPP wave-reduce for
// the scores (VALU pipe, ~10x shorter serial chain than ds_swizzle
// butterfly), ONE combined flash rescale per pair.  #pragma unroll 2 puts
// up to 4 rows in flight.  Month one-hot columns written directly.
// ---------------------------------------------------------------------------
__global__ __launch_bounds__(256) void attn_fused_kernel(
    const int* __restrict__ noun_ids, const int* __restrict__ lengths,
    const int* __restrict__ months, const int* __restrict__ encode_p,
    const float* __restrict__ we, const float* __restrict__ w,
    float* __restrict__ out)
{
    int wave = threadIdx.x >> 6, lane = threadIdx.x & 63;
    int b = blockIdx.x * 4 + wave;
    float4* ob = (float4*)(out + (size_t)b * DH);   // 78 float4, 16B-aligned
    int len = lengths[b];

    if (len <= 0) {                       // reference leaves empty rows zero;
        float4 z = {0.f, 0.f, 0.f, 0.f};  // d_out is poisoned -> must write
        ob[lane] = z;
        if (lane < 14) ob[64 + lane] = z;
        return;                           // len uniform per wave: no divergence
    }
    if (len > LMAX) len = LMAX;

    // w fragment in registers (same cols as this lane's row fragment)
    const float4* w4 = (const float4*)w;
    float4 ww = w4[lane];
    float4 wb = (lane < 11) ? w4[64 + lane] : (float4){0.f, 0.f, 0.f, 0.f};

    int id = (lane < LMAX) ? noun_ids[b * LMAX + lane] : 0;

    float m = -1e30f, denom = 0.f;        // online-softmax state
    float4 acc0 = {0.f, 0.f, 0.f, 0.f};
    float4 acc1 = {0.f, 0.f, 0.f, 0.f};

    #pragma unroll 2
    for (int l = 0; l < len; l += 2) {
        bool dual = (l + 1 < len);
        int rid0 = __shfl(id, l);
        int rid1 = __shfl(id, dual ? (l + 1) : l);  // dup last row on odd tail
        const float4* r0 = (const float4*)(we + (size_t)rid0 * D_WORD);
        const float4* r1 = (const float4*)(we + (size_t)rid1 * D_WORD);
        // issue all four loads up front -> two rows in flight
        float4 A0 = r0[lane];
        float4 B0 = r1[lane];
        float4 A1 = (lane < 11) ? r0[64 + lane] : (float4){0.f, 0.f, 0.f, 0.f};
        float4 B1 = (lane < 11) ? r1[64 + lane] : (float4){0.f, 0.f, 0.f, 0.f};

        // two independent inline partial scores (w pre-scaled by 1/sqrt(128))
        float p0 = fmaf(A0.x, ww.x, fmaf(A0.y, ww.y,
                   fmaf(A0.z, ww.z, fmaf(A0.w, ww.w,
                   fmaf(A1.x, wb.x, fmaf(A1.y, wb.y,
                   fmaf(A1.z, wb.z, A1.w * wb.w)))))));
        float p1 = fmaf(B0.x, ww.x, fmaf(B0.y, ww.y,
                   fmaf(B0.z, ww.z, fmaf(B0.w, ww.w,
                   fmaf(B1.x, wb.x, fmaf(B1.y, wb.y,
                   fmaf(B1.z, wb.z, B1.w * wb.w)))))));
        // DPP wave-reduce (VALU pipe); results wave-uniform (SGPR)
        p0 = wave_sum_uniform(p0);
        p1 = wave_sum_uniform(p1);
        if (!dual) p1 = -1e30f;           // tail: e1 -> 0, B contributes 0

        // ONE combined flash rescale for the pair
        float mn = fmaxf(fmaxf(m, p0), p1);   // v_max3_f32
        float c  = __expf(m  - mn);           // 0 on first iter (m = -1e30)
        float e0 = __expf(p0 - mn);
        float e1 = __expf(p1 - mn);
        m = mn;
        denom = fmaf(denom, c, e0 + e1);
        acc0.x = fmaf(acc0.x, c, fmaf(e0, A0.x, e1 * B0.x));
        acc0.y = fmaf(acc0.y, c, fmaf(e0, A0.y, e1 * B0.y));
        acc0.z = fmaf(acc0.z, c, fmaf(e0, A0.z, e1 * B0.z));
        acc0.w = fmaf(acc0.w, c, fmaf(e0, A0.w, e1 * B0.w));
        acc1.x = fmaf(acc1.x, c, fmaf(e0, A1.x, e1 * B1.x));
        acc1.y = fmaf(acc1.y, c, fmaf(e0, A1.y, e1 * B1.y));
        acc1.z = fmaf(acc1.z, c, fmaf(e0, A1.z, e1 * B1.z));
        acc1.w = fmaf(acc1.w, c, fmaf(e0, A1.w, e1 * B1.w));
    }

    float rs = 1.f / denom;
    acc0.x *= rs; acc0.y *= rs; acc0.z *= rs; acc0.w *= rs;
    ob[lane] = acc0;
    if (lane < 11) {
        acc1.x *= rs; acc1.y *= rs; acc1.z *= rs; acc1.w *= rs;
        ob[64 + lane] = acc1;
    } else if (lane < 14) {
        int mo = months[b];
        float enc = (float)(*encode_p);
        int base = (lane - 11) * 4;
        float4 oh;
        oh.x = (base + 0 == mo) ? enc : 0.f;
        oh.y = (base + 1 == mo) ? enc : 0.f;
        oh.z = (base + 2 == mo) ? enc : 0.f;
        oh.w = (base + 3 == mo) ? enc : 0.f;
        ob[64 + lane] = oh;
    }
}

// ---------------------------------------------------------------------------
extern "C" void kernel_launch(void* const* d_in, const int* in_sizes, int n_in,
                              void* d_out, int out_size, void* d_ws, size_t ws_size,
                              hipStream_t stream) {
    const float* topic_emb = (const float*)d_in[0];
    const int*   noun_ids  = (const int*)d_in[1];
    const int*   lengths   = (const int*)d_in[2];
    const int*   months    = (const int*)d_in[3];
    const int*   encode    = (const int*)d_in[4];
    const float* we        = (const float*)d_in[5];
    const float* k_w       = (const float*)d_in[6];
    // d_in[7] = k_b: cancels in softmax, never touches `value` -> unused.
    const float* q_w       = (const float*)d_in[8];
    const float* q_b       = (const float*)d_in[9];
    float* out = (float*)d_out;

    float* w_vec = (float*)d_ws;         // 312 floats

    compute_w_kernel<<<1, 320, 0, stream>>>(topic_emb, q_w, q_b, k_w, w_vec);
    attn_fused_kernel<<<NB / 4, 256, 0, stream>>>(noun_ids, lengths, months,
                                                  encode, we, w_vec, out);
}

// Round 3
// 132.323 us; speedup vs baseline: 1.0409x; 1.0192x over previous
//
#include <hip/hip_runtime.h>
#include <math.h>

#define VOCAB 50000
#define D_WORD 300
#define D_TOPIC 128
#define DH 312            // D_NOUN_HIDDEN
#define NB 8192
#define LMAX 32
#define N_MONTH 12

// ---------------------------------------------------------------------------
// Wave64 sum-reduce on the VALU pipe via DPP (no LDS-pipe ds_swizzle):
//   row_shr:1/2/4/8 accumulate within each 16-lane row, row_bcast:15/31
//   fold rows; full sum lands in lane 63; v_readlane broadcasts as SGPR.
// ---------------------------------------------------------------------------
__device__ __forceinline__ float wave_sum_uniform(float x) {
    int v = __float_as_int(x);
    int t;
#define DPP_STEP(ctrl)                                                   \
    t = __builtin_amdgcn_update_dpp(0, v, (ctrl), 0xf, 0xf, true);       \
    v = __float_as_int(__int_as_float(v) + __int_as_float(t));
    DPP_STEP(0x111)   // row_shr:1
    DPP_STEP(0x112)   // row_shr:2
    DPP_STEP(0x114)   // row_shr:4
    DPP_STEP(0x118)   // row_shr:8
    DPP_STEP(0x142)   // row_bcast:15
    DPP_STEP(0x143)   // row_bcast:31
#undef DPP_STEP
    return __int_as_float(__builtin_amdgcn_readlane(v, 63));
}

// ---------------------------------------------------------------------------
// Kernel 1 (tiny): w = (k_w^T @ (q_w @ topic_emb + q_b)) * 1/sqrt(128).
// One block, pure latency.  4 independent accumulators per phase break the
// 128-deep serial fma chains (512 cy -> ~128 cy each).
// ---------------------------------------------------------------------------
__global__ __launch_bounds__(320) void compute_w_kernel(
    const float* __restrict__ topic_emb,
    const float* __restrict__ q_w, const float* __restrict__ q_b,
    const float* __restrict__ k_w,
    float* __restrict__ w_out)
{
    __shared__ float query_s[D_TOPIC];
    __shared__ float topic_s[D_TOPIC];
    int t = threadIdx.x;
    if (t < D_TOPIC) topic_s[t] = topic_emb[t];
    __syncthreads();
    if (t < D_TOPIC) {
        const float4* qr = (const float4*)(q_w + t * D_TOPIC);  // row-contig
        float q0 = q_b[t], q1 = 0.f, q2 = 0.f, q3 = 0.f;
        #pragma unroll 8
        for (int k4 = 0; k4 < D_TOPIC / 4; ++k4) {
            float4 v = qr[k4];
            q0 = fmaf(v.x, topic_s[4 * k4 + 0], q0);
            q1 = fmaf(v.y, topic_s[4 * k4 + 1], q1);
            q2 = fmaf(v.z, topic_s[4 * k4 + 2], q2);
            q3 = fmaf(v.w, topic_s[4 * k4 + 3], q3);
        }
        query_s[t] = (q0 + q1) + (q2 + q3);
    }
    __syncthreads();
    if (t < DH) {
        float a0 = 0.f, a1 = 0.f, a2 = 0.f, a3 = 0.f;
        #pragma unroll 8
        for (int d = 0; d < D_TOPIC; d += 4) {        // coalesced over t
            a0 = fmaf(k_w[(d + 0) * DH + t], query_s[d + 0], a0);
            a1 = fmaf(k_w[(d + 1) * DH + t], query_s[d + 1], a1);
            a2 = fmaf(k_w[(d + 2) * DH + t], query_s[d + 2], a2);
            a3 = fmaf(k_w[(d + 3) * DH + t], query_s[d + 3], a3);
        }
        w_out[t] = ((a0 + a1) + (a2 + a3)) * 0.08838834764831845f; // 1/sqrt(128)
    }
}

// ---------------------------------------------------------------------------
// Kernel 2 (fused, single pass): one WAVE per sample, online softmax,
// two tokens per iteration, ONE combined flash rescale per pair.
// NEW: explicit 1-pair-deep software pipeline -- pair l+2's four
// global_load_dwordx4 are issued at the TOP of iteration l and consumed
// only at the rotate at the bottom, so the L2/HBM latency (L3 is cold:
// the harness's 256 MiB poison fill evicts it every iteration) overlaps
// the score/DPP/exp chain instead of serializing with it.
// ---------------------------------------------------------------------------
__global__ __launch_bounds__(256) void attn_fused_kernel(
    const int* __restrict__ noun_ids, const int* __restrict__ lengths,
    const int* __restrict__ months, const int* __restrict__ encode_p,
    const float* __restrict__ we, const float* __restrict__ w,
    float* __restrict__ out)
{
    int wave = threadIdx.x >> 6, lane = threadIdx.x & 63;
    int b = blockIdx.x * 4 + wave;
    float4* ob = (float4*)(out + (size_t)b * DH);   // 78 float4, 16B-aligned
    int len = lengths[b];

    if (len <= 0) {                       // reference leaves empty rows zero;
        float4 z = {0.f, 0.f, 0.f, 0.f};  // d_out is poisoned -> must write
        ob[lane] = z;
        if (lane < 14) ob[64 + lane] = z;
        return;                           // len uniform per wave: no divergence
    }
    if (len > LMAX) len = LMAX;

    // w fragment in registers (same cols as this lane's row fragment)
    const float4* w4 = (const float4*)w;
    float4 ww = w4[lane];
    float4 wb = (lane < 11) ? w4[64 + lane] : (float4){0.f, 0.f, 0.f, 0.f};

    int id = (lane < LMAX) ? noun_ids[b * LMAX + lane] : 0;

    float m = -1e30f, denom = 0.f;        // online-softmax state
    float4 acc0 = {0.f, 0.f, 0.f, 0.f};
    float4 acc1 = {0.f, 0.f, 0.f, 0.f};
    const float4 z4 = {0.f, 0.f, 0.f, 0.f};

    // ---- prologue: issue pair-0 loads --------------------------------
    bool cdual = (len > 1);
    {
        int rid0 = __shfl(id, 0);
        int rid1 = __shfl(id, cdual ? 1 : 0);
        const float4* r0 = (const float4*)(we + (size_t)rid0 * D_WORD);
        const float4* r1 = (const float4*)(we + (size_t)rid1 * D_WORD);
        // fallthrough into loop with current = pair 0
        float4 cA0 = r0[lane];
        float4 cB0 = r1[lane];
        float4 cA1 = (lane < 11) ? r0[64 + lane] : z4;
        float4 cB1 = (lane < 11) ? r1[64 + lane] : z4;

        for (int l = 0; l < len; l += 2) {
            // ---- prefetch pair l+2 (re-fetch current pair on last iter,
            // harmless L1 hits; keeps control flow + loads uniform) ----
            int nl = (l + 2 < len) ? l + 2 : l;
            bool ndual = (nl + 1 < len);
            int nrid0 = __shfl(id, nl);
            int nrid1 = __shfl(id, ndual ? nl + 1 : nl);
            const float4* nr0 = (const float4*)(we + (size_t)nrid0 * D_WORD);
            const float4* nr1 = (const float4*)(we + (size_t)nrid1 * D_WORD);
            float4 nA0 = nr0[lane];
            float4 nB0 = nr1[lane];
            float4 nA1 = (lane < 11) ? nr0[64 + lane] : z4;
            float4 nB1 = (lane < 11) ? nr1[64 + lane] : z4;

            // ---- score current pair (w pre-scaled by 1/sqrt(128)) ----
            float p0 = fmaf(cA0.x, ww.x, fmaf(cA0.y, ww.y,
                       fmaf(cA0.z, ww.z, fmaf(cA0.w, ww.w,
                       fmaf(cA1.x, wb.x, fmaf(cA1.y, wb.y,
                       fmaf(cA1.z, wb.z, cA1.w * wb.w)))))));
            float p1 = fmaf(cB0.x, ww.x, fmaf(cB0.y, ww.y,
                       fmaf(cB0.z, ww.z, fmaf(cB0.w, ww.w,
                       fmaf(cB1.x, wb.x, fmaf(cB1.y, wb.y,
                       fmaf(cB1.z, wb.z, cB1.w * wb.w)))))));
            p0 = wave_sum_uniform(p0);
            p1 = wave_sum_uniform(p1);
            if (!cdual) p1 = -1e30f;      // odd tail: e1 -> 0

            // ---- ONE combined flash rescale for the pair ----
            float mn = fmaxf(fmaxf(m, p0), p1);   // v_max3_f32
            float c  = __expf(m  - mn);           // 0 on first iter
            float e0 = __expf(p0 - mn);
            float e1 = __expf(p1 - mn);
            m = mn;
            denom = fmaf(denom, c, e0 + e1);
            acc0.x = fmaf(acc0.x, c, fmaf(e0, cA0.x, e1 * cB0.x));
            acc0.y = fmaf(acc0.y, c, fmaf(e0, cA0.y, e1 * cB0.y));
            acc0.z = fmaf(acc0.z, c, fmaf(e0, cA0.z, e1 * cB0.z));
            acc0.w = fmaf(acc0.w, c, fmaf(e0, cA0.w, e1 * cB0.w));
            acc1.x = fmaf(acc1.x, c, fmaf(e0, cA1.x, e1 * cB1.x));
            acc1.y = fmaf(acc1.y, c, fmaf(e0, cA1.y, e1 * cB1.y));
            acc1.z = fmaf(acc1.z, c, fmaf(e0, cA1.z, e1 * cB1.z));
            acc1.w = fmaf(acc1.w, c, fmaf(e0, cA1.w, e1 * cB1.w));

            // ---- rotate pipeline ----
            cA0 = nA0; cB0 = nB0; cA1 = nA1; cB1 = nB1; cdual = ndual;
        }
    }

    float rs = 1.f / denom;
    acc0.x *= rs; acc0.y *= rs; acc0.z *= rs; acc0.w *= rs;
    ob[lane] = acc0;
    if (lane < 11) {
        acc1.x *= rs; acc1.y *= rs; acc1.z *= rs; acc1.w *= rs;
        ob[64 + lane] = acc1;
    } else if (lane < 14) {
        int mo = months[b];
        float enc = (float)(*encode_p);
        int base = (lane - 11) * 4;
        float4 oh;
        oh.x = (base + 0 == mo) ? enc : 0.f;
        oh.y = (base + 1 == mo) ? enc : 0.f;
        oh.z = (base + 2 == mo) ? enc : 0.f;
        oh.w = (base + 3 == mo) ? enc : 0.f;
        ob[64 + lane] = oh;
    }
}

// ---------------------------------------------------------------------------
extern "C" void kernel_launch(void* const* d_in, const int* in_sizes, int n_in,
                              void* d_out, int out_size, void* d_ws, size_t ws_size,
                              hipStream_t stream) {
    const float* topic_emb = (const float*)d_in[0];
    const int*   noun_ids  = (const int*)d_in[1];
    const int*   lengths   = (const int*)d_in[2];
    const int*   months    = (const int*)d_in[3];
    const int*   encode    = (const int*)d_in[4];
    const float* we        = (const float*)d_in[5];
    const float* k_w       = (const float*)d_in[6];
    // d_in[7] = k_b: cancels in softmax, never touches `value` -> unused.
    const float* q_w       = (const float*)d_in[8];
    const float* q_b       = (const float*)d_in[9];
    float* out = (float*)d_out;

    float* w_vec = (float*)d_ws;         // 312 floats

    compute_w_kernel<<<1, 320, 0, stream>>>(topic_emb, q_w, q_b, k_w, w_vec);
    attn_fused_kernel<<<NB / 4, 256, 0, stream>>>(noun_ids, lengths, months,
                                                  encode, we, w_vec, out);
}